// Round 2
// baseline (543.602 us; speedup 1.0000x reference)
//
#include <hip/hip_runtime.h>

#define S_VOX (128*128*128)   // spatial voxels per (b,n) plane = 2097152
#define QV (S_VOX/4)          // float4 groups per plane = 524288
#define EPSF 1e-10f
#define SMOOTHF 1e-5f
#define NACC 49               // [0]=ce, [1..16]=inter, [17..32]=ground, [33..48]=pred_o
#define NBLK 2048             // NBLK*256 == QV exactly
#define LN2F 0.69314718056f

// ws layout (floats): [0..48] accumulators, [49] = u32 done-counter

__global__ __launch_bounds__(256, 2) void dice_main(const float* __restrict__ pred,
                                                    const int* __restrict__ tgt,
                                                    float* __restrict__ ws,
                                                    float* __restrict__ out) {
    const float4* p4 = (const float4*)pred;
    const int4*   t4 = (const int4*)tgt;
    const int q = blockIdx.x * 256 + threadIdx.x;   // grid covers QV exactly

    // ---- issue ALL loads up front (18 streams, independent) ----
    const int4 T0 = t4[q];
    const int4 T1 = t4[QV + q];
    float4 A[8], B[8];
#pragma unroll
    for (int n = 0; n < 8; n++) A[n] = p4[n * QV + q];
#pragma unroll
    for (int n = 0; n < 8; n++) B[n] = p4[(8 + n) * QV + q];

    // ---- compute ----
    float i0[8], i1[8], g0[8], g1[8], po0[8], po1[8];
    // running selections: pred[b'][t_b] for the 4 voxels (init = class 0)
    float s00x = A[0].x, s00y = A[0].y, s00z = A[0].z, s00w = A[0].w; // pred0[t0]
    float s01x = B[0].x, s01y = B[0].y, s01z = B[0].z, s01w = B[0].w; // pred1[t0]
    float s10x = A[0].x, s10y = A[0].y, s10z = A[0].z, s10w = A[0].w; // pred0[t1]
    float s11x = B[0].x, s11y = B[0].y, s11z = B[0].z, s11w = B[0].w; // pred1[t1]

#pragma unroll
    for (int n = 0; n < 8; n++) {
        const float4 a = A[n];
        const float4 b = B[n];
        po0[n] = (a.x + a.y) + (a.z + a.w);
        po1[n] = (b.x + b.y) + (b.z + b.w);

        float ii0 = 0.f, ii1 = 0.f, gg0 = 0.f, gg1 = 0.f;
#define VOX(c)                                                          \
        {                                                               \
            const bool m0 = (T0.c == n);                                \
            const bool m1 = (T1.c == n);                                \
            if (n > 0) {                                                \
                s00##c = m0 ? a.c : s00##c;                             \
                s01##c = m0 ? b.c : s01##c;                             \
                s10##c = m1 ? a.c : s10##c;                             \
                s11##c = m1 ? b.c : s11##c;                             \
            }                                                           \
            ii0 += m0 ? a.c : 0.f;                                      \
            ii1 += m1 ? b.c : 0.f;                                      \
            gg0 += m0 ? 1.f : 0.f;                                      \
            gg1 += m1 ? 1.f : 0.f;                                      \
        }
        VOX(x) VOX(y) VOX(z) VOX(w)
#undef VOX
        i0[n] = ii0; i1[n] = ii1; g0[n] = gg0; g1[n] = gg1;
    }

    // CE: 4 selected values per voxel-quad component, natural log via v_log_f32
    const float ce = LN2F *
        ( (__log2f(s00x + EPSF) + __log2f(s01x + EPSF) + __log2f(s10x + EPSF) + __log2f(s11x + EPSF))
        + (__log2f(s00y + EPSF) + __log2f(s01y + EPSF) + __log2f(s10y + EPSF) + __log2f(s11y + EPSF))
        + (__log2f(s00z + EPSF) + __log2f(s01z + EPSF) + __log2f(s10z + EPSF) + __log2f(s11z + EPSF))
        + (__log2f(s00w + EPSF) + __log2f(s01w + EPSF) + __log2f(s10w + EPSF) + __log2f(s11w + EPSF)) );

    // ---- pack 49 accumulators ----
    float acc[NACC];
    acc[0] = ce;
#pragma unroll
    for (int n = 0; n < 8; n++) {
        acc[1  + n] = i0[n];  acc[9  + n] = i1[n];
        acc[17 + n] = g0[n];  acc[25 + n] = g1[n];
        acc[33 + n] = po0[n]; acc[41 + n] = po1[n];
    }

    // ---- block reduction: 2 shuffle stages -> 16 lanes -> LDS -> 49 threads ----
    __shared__ float lds[64 * 53];   // 64 lane-groups x 49 (pad 53: odd stride, conflict-free)
    const int lane = threadIdx.x & 63;
    const int wave = threadIdx.x >> 6;
#pragma unroll
    for (int i = 0; i < NACC; i++) {
        float v = acc[i];
        v += __shfl_down(v, 32, 64);
        v += __shfl_down(v, 16, 64);
        if (lane < 16) lds[(wave * 16 + lane) * 53 + i] = v;
    }
    __syncthreads();
    if (threadIdx.x < NACC) {
        float s = 0.f;
#pragma unroll
        for (int k = 0; k < 64; k++) s += lds[k * 53 + threadIdx.x];
        atomicAdd(&ws[threadIdx.x], s);
    }

    // ---- last-block-done finalize ----
    __threadfence();
    __syncthreads();
    if (threadIdx.x == 0) {
        const unsigned prev = atomicAdd((unsigned int*)(ws + NACC), 1u);
        if (prev == (unsigned)(gridDim.x - 1)) {
            float v[NACC];
#pragma unroll
            for (int i = 0; i < NACC; i++) v[i] = atomicAdd(&ws[i], 0.0f); // coherent read
            float dice = 0.f;
#pragma unroll
            for (int k = 0; k < 16; k++)
                dice += 1.0f - (2.0f * v[1 + k] + SMOOTHF) / (v[17 + k] + v[33 + k] + SMOOTHF);
            out[0] = -v[0] / (4.0f * (float)S_VOX) + dice * (1.0f / 16.0f);
        }
    }
}

extern "C" void kernel_launch(void* const* d_in, const int* in_sizes, int n_in,
                              void* d_out, int out_size, void* d_ws, size_t ws_size,
                              hipStream_t stream) {
    const float* pred = (const float*)d_in[0];
    const int*   tgt  = (const int*)d_in[1];
    float* ws  = (float*)d_ws;
    float* out = (float*)d_out;

    hipMemsetAsync(ws, 0, (NACC + 1) * sizeof(float), stream);
    dice_main<<<NBLK, 256, 0, stream>>>(pred, tgt, ws, out);
}

// Round 3
// 353.607 us; speedup vs baseline: 1.5373x; 1.5373x over previous
//
#include <hip/hip_runtime.h>

#define S_VOX (128*128*128)   // voxels per (b,n) plane
#define QV (S_VOX/4)          // float4 groups per plane = 524288
#define EPSF 1e-10f
#define SMOOTHF 1e-5f
#define NACC 49               // [0]=ce(log2), [1..16]=inter, [17..32]=ground, [33..48]=pred_o
#define LN2F 0.6931471805599453f

#define CHUNKS 128            // blocks per plane
#define CGROUPS (QV/CHUNKS)   // float4 groups per chunk = 4096
#define ITERS (CGROUPS/256)   // groups per thread = 16

// ------------------------------------------------------------------
// Kernel A: pack both batches' 3-bit targets for a voxel-quad into one u32
// bits [6c..6c+2] = t0.c, [6c+3..6c+5] = t1.c   (c = component 0..3)
// Also zeroes ws (block 0) so no separate memset node is needed.
// ------------------------------------------------------------------
__global__ __launch_bounds__(256) void pack_targets(const int* __restrict__ tgt,
                                                    unsigned int* __restrict__ packed,
                                                    float* __restrict__ ws) {
    if (blockIdx.x == 0 && threadIdx.x <= NACC) ws[threadIdx.x] = 0.f;
    const int4* t4 = (const int4*)tgt;
    int q = blockIdx.x * 1024 + threadIdx.x;
#pragma unroll
    for (int i = 0; i < 4; i++, q += 256) {
        const int4 t0 = t4[q];
        const int4 t1 = t4[QV + q];
        unsigned int m = (unsigned)(t0.x & 7)        | ((unsigned)(t1.x & 7) << 3)
                       | ((unsigned)(t0.y & 7) << 6) | ((unsigned)(t1.y & 7) << 9)
                       | ((unsigned)(t0.z & 7) << 12)| ((unsigned)(t1.z & 7) << 15)
                       | ((unsigned)(t0.w & 7) << 18)| ((unsigned)(t1.w & 7) << 21);
        packed[q] = m;
    }
}

// ------------------------------------------------------------------
// Kernel B: stream one (b,n) plane chunk per block. 4 scalar accumulators.
// ------------------------------------------------------------------
__global__ __launch_bounds__(256) void dice_main(const float* __restrict__ pred,
                                                 const unsigned int* __restrict__ packed,
                                                 float* __restrict__ ws,
                                                 float* __restrict__ out) {
    const int plane = blockIdx.x & 15;        // (b,n): b = plane>>3, n = plane&7
    const int chunk = blockIdx.x >> 4;        // [0,128)
    const int b     = plane >> 3;
    const int n     = plane & 7;

    const float4* p4 = (const float4*)pred + (size_t)plane * QV;
    const int q0 = chunk * CGROUPS + threadIdx.x;

    float ce = 0.f, inter = 0.f, gnd = 0.f, po = 0.f;

#pragma unroll
    for (int it = 0; it < ITERS; it += 4) {
        const int qa = q0 + (it + 0) * 256;
        const int qb = q0 + (it + 1) * 256;
        const int qc = q0 + (it + 2) * 256;
        const int qd = q0 + (it + 3) * 256;
        // issue all 8 loads before consuming
        const float4 pA = p4[qa]; const float4 pB = p4[qb];
        const float4 pC = p4[qc]; const float4 pD = p4[qd];
        const unsigned mA = packed[qa]; const unsigned mB = packed[qb];
        const unsigned mC = packed[qc]; const unsigned mD = packed[qd];

#define COMP(p, m, sh)                                                   \
        {                                                                \
            const int e0 = (int)((m >> (sh))     & 7u);                  \
            const int e1 = (int)((m >> ((sh)+3)) & 7u);                  \
            const int c0 = (e0 == n);                                    \
            const int c1 = (e1 == n);                                    \
            const float lg = __log2f((p) + EPSF);                        \
            ce += (float)(c0 + c1) * lg;                                 \
            const int mb = b ? c1 : c0;                                  \
            inter += mb ? (p) : 0.f;                                     \
            gnd   += (float)mb;                                          \
            po    += (p);                                                \
        }
#define GROUP(pv, mv)                                                    \
        COMP(pv.x, mv, 0) COMP(pv.y, mv, 6) COMP(pv.z, mv, 12) COMP(pv.w, mv, 18)

        GROUP(pA, mA) GROUP(pB, mB) GROUP(pC, mC) GROUP(pD, mD)
#undef GROUP
#undef COMP
    }

    // ---- block reduction: full 64-lane shuffle per value -> LDS -> atomics ----
    __shared__ float red[4][4];
    const int lane = threadIdx.x & 63;
    const int wave = threadIdx.x >> 6;
    float v[4] = {ce, inter, gnd, po};
#pragma unroll
    for (int i = 0; i < 4; i++) {
#pragma unroll
        for (int off = 32; off > 0; off >>= 1)
            v[i] += __shfl_down(v[i], off, 64);
        if (lane == 0) red[wave][i] = v[i];
    }
    __syncthreads();
    if (threadIdx.x < 4) {
        const float s = red[0][threadIdx.x] + red[1][threadIdx.x] +
                        red[2][threadIdx.x] + red[3][threadIdx.x];
        const int slot = (threadIdx.x == 0) ? 0
                       : (threadIdx.x == 1) ? (1 + plane)
                       : (threadIdx.x == 2) ? (17 + plane)
                       : (33 + plane);
        atomicAdd(&ws[slot], s);
    }

    // ---- last-block finalize ----
    __threadfence();
    __syncthreads();
    if (threadIdx.x == 0) {
        const unsigned prev = atomicAdd((unsigned int*)(ws + NACC), 1u);
        if (prev == (unsigned)(gridDim.x - 1)) {
            float acc[NACC];
#pragma unroll
            for (int i = 0; i < NACC; i++) acc[i] = atomicAdd(&ws[i], 0.0f); // coherent read
            float dice = 0.f;
#pragma unroll
            for (int k = 0; k < 16; k++)
                dice += 1.0f - (2.0f * acc[1 + k] + SMOOTHF) / (acc[17 + k] + acc[33 + k] + SMOOTHF);
            out[0] = -(acc[0] * LN2F) / (4.0f * (float)S_VOX) + dice * (1.0f / 16.0f);
        }
    }
}

extern "C" void kernel_launch(void* const* d_in, const int* in_sizes, int n_in,
                              void* d_out, int out_size, void* d_ws, size_t ws_size,
                              hipStream_t stream) {
    const float* pred = (const float*)d_in[0];
    const int*   tgt  = (const int*)d_in[1];
    float*        ws     = (float*)d_ws;                 // [0..49]
    unsigned int* packed = (unsigned int*)(ws + 64);     // QV u32 = 2 MB scratch
    float* out = (float*)d_out;

    pack_targets<<<QV / 1024, 256, 0, stream>>>(tgt, packed, ws);
    dice_main<<<16 * CHUNKS, 256, 0, stream>>>(pred, packed, ws, out);
}